// Round 5
// baseline (104.469 us; speedup 1.0000x reference)
//
#include <hip/hip_runtime.h>

typedef __attribute__((ext_vector_type(8)))  short   short8;
typedef __attribute__((ext_vector_type(4)))  unsigned uint4v;
typedef __attribute__((ext_vector_type(16))) float   f32x16;
typedef __attribute__((ext_vector_type(4)))  float   f4;

constexpr int NBLOCK     = 512;           // 2 blocks/CU exactly
constexpr int BLOCK      = 256;           // 4 waves
constexpr int CHUNK_F    = 3072;          // 16 slabs x 192 floats = 12 KiB
constexpr int CPW        = 8;             // chunks per wave (512*4*8 = 16384 = NCHUNK)
constexpr int RED_BLOCKS = 96;            // reducer blocks (32 gram cols each)
constexpr int MSE_ITERS  = 16;            // 16 * 512 * 256 f4 = 2^21 = all of X/Y

// ws float-offsets:
//   [0..512)        MSE per-block partials (plain stores)
//   [512..1024)     512 stage-1 flags (int; writers store 1, block0 resets 0)
//   [1024..1120)    96 stage-2 flags
//   [1152..4224)    gram_final (3072)
//   [4608.. +512*3072) per-block gram partial tiles
constexpr int MSE_OFF  = 0;
constexpr int F1_OFF   = 512;
constexpr int F2_OFF   = 1024;
constexpr int GF_OFF   = 1152;
constexpr int PART_OFF = 4608;

struct F3 { float v[3]; };                 // 12B -> global_load_dwordx3
struct Chunk { F3 a0[4], a1[4], b0[4], b1[4]; };

// pack two f32 -> one u32 of 2 bf16 (round-half-up): 2 add + 1 v_perm
__device__ __forceinline__ unsigned pk_bf16(float a, float b) {
  unsigned a2 = __builtin_bit_cast(unsigned, a) + 0x8000u;
  unsigned b2 = __builtin_bit_cast(unsigned, b) + 0x8000u;
  return __builtin_amdgcn_perm(b2, a2, 0x07060302u);
}

__device__ __forceinline__ void load_chunk(const float* __restrict__ W, int c,
                                           int laneoff, Chunk& ch) {
  const float* s = W + (size_t)c * CHUNK_F + laneoff;
#pragma unroll
  for (int bp = 0; bp < 4; ++bp) {
    const float* p = s + bp * 384;     // slab pair (2bp, 2bp+1) of this half
    ch.a0[bp] = *(const F3*)(p);       // slab even, row r
    ch.a1[bp] = *(const F3*)(p + 96);  // slab even, row r+32
    ch.b0[bp] = *(const F3*)(p + 192); // slab odd,  row r
    ch.b1[bp] = *(const F3*)(p + 288); // slab odd,  row r+32
  }
}

__device__ __forceinline__ void mac_chunk(const Chunk& c, f32x16& a00, f32x16& a01,
                                          f32x16& a11) {
#pragma unroll
  for (int k = 0; k < 3; ++k) {
    unsigned fl[4], fh[4];
#pragma unroll
    for (int bp = 0; bp < 4; ++bp) {
      fl[bp] = pk_bf16(c.a0[bp].v[k], c.b0[bp].v[k]);
      fh[bp] = pk_bf16(c.a1[bp].v[k], c.b1[bp].v[k]);
    }
    uint4v vl = {fl[0], fl[1], fl[2], fl[3]};
    uint4v vh = {fh[0], fh[1], fh[2], fh[3]};
    short8 lo = __builtin_bit_cast(short8, vl);
    short8 hv = __builtin_bit_cast(short8, vh);
    a00 = __builtin_amdgcn_mfma_f32_32x32x16_bf16(lo, lo, a00, 0, 0, 0);
    a01 = __builtin_amdgcn_mfma_f32_32x32x16_bf16(lo, hv, a01, 0, 0, 0);
    a11 = __builtin_amdgcn_mfma_f32_32x32x16_bf16(hv, hv, a11, 0, 0, 0);
  }
}

__global__ __launch_bounds__(BLOCK, 2) void k_all(
    const float* __restrict__ X, const float* __restrict__ Y,
    const float* __restrict__ W, float* __restrict__ ws,
    float* __restrict__ out) {
  __shared__ __align__(16) float red[2][3072];   // 24 KiB
  __shared__ float r2[4][32];
  __shared__ float n2[64];
  __shared__ float fsum[4];
  const int bid  = blockIdx.x;
  const int tid  = threadIdx.x;
  const int wave = tid >> 6;
  const int lane = tid & 63;
  const int r    = lane & 31;
  const int hi   = lane >> 5;
  int* flag1 = (int*)(ws + F1_OFF);
  int* flag2 = (int*)(ws + F2_OFF);

  // ================= phase 1a: gram — 8 chunks/wave, reg double-buffer =========
  const int laneoff = hi * 1536 + 3 * r;   // (hi*8 slabs)*192 + row r
  const int c0 = bid * 32 + wave * 8;

  f32x16 a00{}, a01{}, a11{};
  Chunk ca, cb;
  load_chunk(W, c0, laneoff, ca);
#pragma unroll
  for (int t = 0; t < CPW; t += 2) {
    load_chunk(W, c0 + t + 1, laneoff, cb);
    mac_chunk(ca, a00, a01, a11);
    if (t + 2 < CPW) load_chunk(W, c0 + t + 2, laneoff, ca);
    mac_chunk(cb, a00, a01, a11);
  }

  // block reduce 4 waves -> 2 -> coalesced partial-tile store
  if (wave < 2) {
#pragma unroll
    for (int rg = 0; rg < 16; ++rg) {
      red[wave][       rg * 64 + lane] = a00[rg];
      red[wave][1024 + rg * 64 + lane] = a01[rg];
      red[wave][2048 + rg * 64 + lane] = a11[rg];
    }
  }
  __syncthreads();
  if (wave >= 2) {
    float* dst = red[wave - 2];
#pragma unroll
    for (int rg = 0; rg < 16; ++rg) {
      dst[       rg * 64 + lane] += a00[rg];
      dst[1024 + rg * 64 + lane] += a01[rg];
      dst[2048 + rg * 64 + lane] += a11[rg];
    }
  }
  __syncthreads();
  {
    const f4* r0 = (const f4*)&red[0][0];
    const f4* r1 = (const f4*)&red[1][0];
    f4* p4 = (f4*)(ws + PART_OFF + (size_t)bid * 3072);
#pragma unroll
    for (int q = tid; q < 768; q += BLOCK) p4[q] = r0[q] + r1[q];
  }

  // ================= phase 1b: MSE — 16 grid-sweep float4 iters ================
  {
    const f4* x4 = (const f4*)X;
    const f4* y4 = (const f4*)Y;
    float acc = 0.f;
#pragma unroll 8
    for (int j = 0; j < MSE_ITERS; ++j) {
      unsigned i = (unsigned)j * (unsigned)(NBLOCK * BLOCK) +
                   (unsigned)bid * BLOCK + (unsigned)tid;
      f4 a = __builtin_nontemporal_load(x4 + i);
      f4 b = __builtin_nontemporal_load(y4 + i);
      float d0 = a[0] - b[0], d1 = a[1] - b[1], d2 = a[2] - b[2], d3 = a[3] - b[3];
      acc += d0 * d0 + d1 * d1 + d2 * d2 + d3 * d3;
    }
#pragma unroll
    for (int o = 32; o; o >>= 1) acc += __shfl_xor(acc, o, 64);
    if (lane == 0) fsum[wave] = acc;
    __syncthreads();
    if (tid == 0) ws[MSE_OFF + bid] = fsum[0] + fsum[1] + fsum[2] + fsum[3];
  }

  // publish stage-1 (syncthreads drained vmcnt; threadfence writes back L2)
  __syncthreads();
  if (tid == 0) {
    __threadfence();
    __hip_atomic_store(&flag1[bid], 1, __ATOMIC_RELEASE, __HIP_MEMORY_SCOPE_AGENT);
  }

  // ================= phase 2: 96 reducers (32 gram cols each) ==================
  if (bid >= RED_BLOCKS) return;
  for (int f = tid; f < NBLOCK; f += BLOCK)
    while (__hip_atomic_load(&flag1[f], __ATOMIC_RELAXED,
                             __HIP_MEMORY_SCOPE_AGENT) != 1)
      __builtin_amdgcn_s_sleep(4);
  __syncthreads();
  __threadfence();

  {
    const int el = lane & 31, ph = lane >> 5;
    const int w0 = bid * 32;
    const float* base = ws + PART_OFF + (size_t)(ph + 2 * wave) * 3072 + w0 + el;
    float acc = 0.f;
#pragma unroll 8
    for (int i = 0; i < 64; ++i) acc += base[(size_t)i * 24576];
    acc += __shfl_xor(acc, 32, 64);
    if (ph == 0) r2[wave][el] = acc;
    __syncthreads();
    if (tid < 32)
      ws[GF_OFF + w0 + tid] = r2[0][tid] + r2[1][tid] + r2[2][tid] + r2[3][tid];
  }
  __syncthreads();
  if (tid == 0) {
    __threadfence();
    __hip_atomic_store(&flag2[bid], 1, __ATOMIC_RELEASE, __HIP_MEMORY_SCOPE_AGENT);
  }

  // ================= phase 3: block 0 finalizes ================================
  if (bid != 0) return;
  if (tid < RED_BLOCKS)
    while (__hip_atomic_load(&flag2[tid], __ATOMIC_RELAXED,
                             __HIP_MEMORY_SCOPE_AGENT) != 1)
      __builtin_amdgcn_s_sleep(4);
  __syncthreads();
  __threadfence();

  float* g = &red[0][0];                       // reuse LDS
  for (int e = tid; e < 3072; e += BLOCK) g[e] = ws[GF_OFF + e];

  float m = ws[MSE_OFF + tid] + ws[MSE_OFF + 256 + tid];
#pragma unroll
  for (int o = 32; o; o >>= 1) m += __shfl_xor(m, o, 64);
  if (lane == 0) fsum[wave] = m;

  // reset flags for the next replay (all writers are provably done)
  for (int f = tid; f < NBLOCK; f += BLOCK) flag1[f] = 0;
  if (tid < RED_BLOCKS) flag2[tid] = 0;
  __syncthreads();

  // C/D layout of 32x32 mfma: col = lane&31, row = (reg&3) + 8*(reg>>2) + 4*(lane>>5)
  for (int e = tid; e < 3072; e += BLOCK) {
    int tl = e >> 10, rg = (e >> 6) & 15, l = e & 63;
    int il = (rg & 3) + 8 * (rg >> 2) + 4 * (l >> 5);
    int jl = l & 31;
    if (tl != 1 && il == jl) n2[il + (tl == 2 ? 32 : 0)] = g[e];
  }
  __syncthreads();

  float local = 0.f;
  for (int e = tid; e < 3072; e += BLOCK) {
    int tl = e >> 10, rg = (e >> 6) & 15, l = e & 63;
    int il = (rg & 3) + 8 * (rg >> 2) + 4 * (l >> 5);
    int jl = l & 31;
    int i, j; float wgt;
    if (tl == 0)      { i = il;      j = jl;      wgt = 1.f; }
    else if (tl == 1) { i = il;      j = jl + 32; wgt = 2.f; }  // symmetric quadrant
    else              { i = il + 32; j = jl + 32; wgt = 1.f; }
    if (i != j) {
      float sim = g[e] / sqrtf(n2[i] * n2[j]);
      if (sim > 0.2f && sim <= 1.0f) local += wgt * sim;
    }
  }
#pragma unroll
  for (int o = 32; o; o >>= 1) local += __shfl_xor(local, o, 64);
  __shared__ float wsum[4];
  if (lane == 0) wsum[wave] = local;
  __syncthreads();
  if (tid == 0) {
    float reg_sum = wsum[0] + wsum[1] + wsum[2] + wsum[3];
    float mse_sum = fsum[0] + fsum[1] + fsum[2] + fsum[3];
    out[0] = mse_sum * (1.0f / 8388608.0f) + 0.0005f * reg_sum;
  }
}

extern "C" void kernel_launch(void* const* d_in, const int* in_sizes, int n_in,
                              void* d_out, int out_size, void* d_ws, size_t ws_size,
                              hipStream_t stream) {
  const float* X = (const float*)d_in[0];
  const float* Y = (const float*)d_in[1];
  const float* W = (const float*)d_in[2];
  k_all<<<NBLOCK, BLOCK, 0, stream>>>(X, Y, W, (float*)d_ws, (float*)d_out);
}

// Round 6
// 76.302 us; speedup vs baseline: 1.3692x; 1.3692x over previous
//
#include <hip/hip_runtime.h>

typedef __attribute__((ext_vector_type(8)))  short   short8;
typedef __attribute__((ext_vector_type(4)))  unsigned uint4v;
typedef __attribute__((ext_vector_type(16))) float   f32x16;
typedef __attribute__((ext_vector_type(4)))  float   f4;

constexpr int NB         = 256;     // 1 block/CU exactly
constexpr int BLOCK      = 1024;    // 16 waves
constexpr int CHUNK_F    = 3072;    // 16 slabs x 192 floats = 12 KiB
constexpr int CPW        = 4;       // chunks/wave: 256*16*4 = 16384 = NCHUNK
constexpr int RED_BLOCKS = 96;

// ws float-offsets:
//   [0..256)     MSE per-block partials (plain stores)
//   [256..352)   96 k_b flags (writers store 1 w/ release; block0 resets 0)
//   [512..3584)  gram_final (3072)
//   [4096..4096+256*3072) per-block gram partial tiles (plain stores)
constexpr int MSE_OFF  = 0;
constexpr int FLAG_OFF = 256;
constexpr int GF_OFF   = 512;
constexpr int PART_OFF = 4096;

struct F3 { float v[3]; };                 // 12B -> global_load_dwordx3
struct Chunk { F3 a0[4], a1[4], b0[4], b1[4]; };

// pack two f32 -> one u32 of 2 bf16 (round-half-up): 2 add + 1 v_perm
__device__ __forceinline__ unsigned pk_bf16(float a, float b) {
  unsigned a2 = __builtin_bit_cast(unsigned, a) + 0x8000u;
  unsigned b2 = __builtin_bit_cast(unsigned, b) + 0x8000u;
  return __builtin_amdgcn_perm(b2, a2, 0x07060302u);
}

__device__ __forceinline__ void load_chunk(const float* __restrict__ W, int c,
                                           int laneoff, Chunk& ch) {
  const float* s = W + (size_t)c * CHUNK_F + laneoff;
#pragma unroll
  for (int bp = 0; bp < 4; ++bp) {
    const float* p = s + bp * 384;     // slab pair (2bp, 2bp+1) of this half
    ch.a0[bp] = *(const F3*)(p);       // slab even, row r
    ch.a1[bp] = *(const F3*)(p + 96);  // slab even, row r+32
    ch.b0[bp] = *(const F3*)(p + 192); // slab odd,  row r
    ch.b1[bp] = *(const F3*)(p + 288); // slab odd,  row r+32
  }
}

__device__ __forceinline__ void mac_chunk(const Chunk& c, f32x16& a00, f32x16& a01,
                                          f32x16& a11) {
#pragma unroll
  for (int k = 0; k < 3; ++k) {
    unsigned fl[4], fh[4];
#pragma unroll
    for (int bp = 0; bp < 4; ++bp) {
      fl[bp] = pk_bf16(c.a0[bp].v[k], c.b0[bp].v[k]);
      fh[bp] = pk_bf16(c.a1[bp].v[k], c.b1[bp].v[k]);
    }
    uint4v vl = {fl[0], fl[1], fl[2], fl[3]};
    uint4v vh = {fh[0], fh[1], fh[2], fh[3]};
    short8 lo = __builtin_bit_cast(short8, vl);
    short8 hv = __builtin_bit_cast(short8, vh);
    a00 = __builtin_amdgcn_mfma_f32_32x32x16_bf16(lo, lo, a00, 0, 0, 0);
    a01 = __builtin_amdgcn_mfma_f32_32x32x16_bf16(lo, hv, a01, 0, 0, 0);
    a11 = __builtin_amdgcn_mfma_f32_32x32x16_bf16(hv, hv, a11, 0, 0, 0);
  }
}

__device__ __forceinline__ float mse2(const f4* x4, const f4* y4, int i0) {
  f4 xa = __builtin_nontemporal_load(x4 + i0 * 64);
  f4 ya = __builtin_nontemporal_load(y4 + i0 * 64);
  f4 xb = __builtin_nontemporal_load(x4 + (i0 + 1) * 64);
  f4 yb = __builtin_nontemporal_load(y4 + (i0 + 1) * 64);
  f4 d0 = xa - ya, d1 = xb - yb;
  return d0[0]*d0[0] + d0[1]*d0[1] + d0[2]*d0[2] + d0[3]*d0[3] +
         d1[0]*d1[0] + d1[1]*d1[1] + d1[2]*d1[2] + d1[3]*d1[3];
}

__global__ __launch_bounds__(BLOCK, 4) void k_a(
    const float* __restrict__ X, const float* __restrict__ Y,
    const float* __restrict__ W, float* __restrict__ ws) {
  __shared__ __align__(16) float red[4][3072];   // 48 KiB
  __shared__ float fsum[16];
  const int bid  = blockIdx.x;
  const int tid  = threadIdx.x;
  const int wave = tid >> 6;
  const int lane = tid & 63;
  const int r    = lane & 31;
  const int hi   = lane >> 5;
  const int wid  = bid * 16 + wave;          // global wave id 0..4095
  const int laneoff = hi * 1536 + 3 * r;     // (hi*8 slabs)*192 + row r
  const int c0 = wid * CPW;
  const f4* x4 = (const f4*)X + (size_t)wid * 512 + lane;
  const f4* y4 = (const f4*)Y + (size_t)wid * 512 + lane;

  // ---- interleaved dual stream: 4 W-chunks + 8 MSE f4-iters per wave ----
  f32x16 a00{}, a01{}, a11{};
  float macc = 0.f;
  Chunk ca, cb;
  load_chunk(W, c0, laneoff, ca);
#pragma unroll
  for (int t = 0; t < CPW; t += 2) {
    load_chunk(W, c0 + t + 1, laneoff, cb);
    macc += mse2(x4, y4, 2 * t);
    mac_chunk(ca, a00, a01, a11);
    if (t + 2 < CPW) load_chunk(W, c0 + t + 2, laneoff, ca);
    macc += mse2(x4, y4, 2 * t + 2);
    mac_chunk(cb, a00, a01, a11);
  }

  // ---- MSE wave reduce ----
#pragma unroll
  for (int o = 32; o; o >>= 1) macc += __shfl_xor(macc, o, 64);
  if (lane == 0) fsum[wave] = macc;

  // ---- gram block reduce: 16 waves -> 4 LDS rows (4 rounds) -> tile store ----
#pragma unroll
  for (int rd = 0; rd < 4; ++rd) {
    if ((wave >> 2) == rd) {
      float* dst = red[wave & 3];
      if (rd == 0) {
#pragma unroll
        for (int rg = 0; rg < 16; ++rg) {
          dst[       rg * 64 + lane] = a00[rg];
          dst[1024 + rg * 64 + lane] = a01[rg];
          dst[2048 + rg * 64 + lane] = a11[rg];
        }
      } else {
#pragma unroll
        for (int rg = 0; rg < 16; ++rg) {
          dst[       rg * 64 + lane] += a00[rg];
          dst[1024 + rg * 64 + lane] += a01[rg];
          dst[2048 + rg * 64 + lane] += a11[rg];
        }
      }
    }
    __syncthreads();
  }
  {
    const f4* r0 = (const f4*)&red[0][0];
    const f4* r1 = (const f4*)&red[1][0];
    const f4* r2 = (const f4*)&red[2][0];
    const f4* r3 = (const f4*)&red[3][0];
    f4* p4 = (f4*)(ws + PART_OFF + (size_t)bid * 3072);
    if (tid < 768) p4[tid] = r0[tid] + r1[tid] + r2[tid] + r3[tid];
  }
  if (tid == 0) {
    float m = 0.f;
#pragma unroll
    for (int wv = 0; wv < 16; ++wv) m += fsum[wv];
    ws[MSE_OFF + bid] = m;
  }
}

__global__ __launch_bounds__(256) void k_b(float* __restrict__ ws,
                                           float* __restrict__ out) {
  __shared__ float r2[4][32];
  __shared__ float g[3072];
  __shared__ float n2[64];
  __shared__ float msum_s[4];
  __shared__ float wsum[4];
  const int tid = threadIdx.x;
  const int lane = tid & 63, wv = tid >> 6, el = lane & 31, ph = lane >> 5;
  const int b = blockIdx.x;
  const int w0 = b * 32;
  int* flags = (int*)(ws + FLAG_OFF);

  // ---- reduce 256 partial tiles over this block's 32-col window ----
  const float* base = ws + PART_OFF + (size_t)(ph + 2 * wv) * 3072 + w0 + el;
  float acc = 0.f;
#pragma unroll 8
  for (int i = 0; i < 32; ++i) acc += base[(size_t)i * 24576];
  acc += __shfl_xor(acc, 32, 64);
  if (ph == 0) r2[wv][el] = acc;
  __syncthreads();
  if (tid < 32)
    ws[GF_OFF + w0 + tid] = r2[0][tid] + r2[1][tid] + r2[2][tid] + r2[3][tid];
  __syncthreads();   // drains stores before publishing
  if (tid == 0) {
    __threadfence();
    __hip_atomic_store(&flags[b], 1, __ATOMIC_RELEASE, __HIP_MEMORY_SCOPE_AGENT);
  }
  if (b != 0) return;

  // ---- block 0: wait for all 96 windows, then finalize ----
  if (tid < RED_BLOCKS)
    while (__hip_atomic_load(&flags[tid], __ATOMIC_RELAXED,
                             __HIP_MEMORY_SCOPE_AGENT) != 1)
      __builtin_amdgcn_s_sleep(8);
  __syncthreads();
  __threadfence();

  for (int e = tid; e < 3072; e += 256) g[e] = ws[GF_OFF + e];

  float m = ws[MSE_OFF + tid];
#pragma unroll
  for (int o = 32; o; o >>= 1) m += __shfl_xor(m, o, 64);
  if (lane == 0) msum_s[wv] = m;
  __syncthreads();

  // reset flags for the next replay (all writers provably done)
  if (tid < RED_BLOCKS) flags[tid] = 0;

  // C/D layout of 32x32 mfma: col = lane&31, row = (reg&3) + 8*(reg>>2) + 4*(lane>>5)
  for (int e = tid; e < 3072; e += 256) {
    int tl = e >> 10, rg = (e >> 6) & 15, l = e & 63;
    int il = (rg & 3) + 8 * (rg >> 2) + 4 * (l >> 5);
    int jl = l & 31;
    if (tl != 1 && il == jl) n2[il + (tl == 2 ? 32 : 0)] = g[e];
  }
  __syncthreads();

  float local = 0.f;
  for (int e = tid; e < 3072; e += 256) {
    int tl = e >> 10, rg = (e >> 6) & 15, l = e & 63;
    int il = (rg & 3) + 8 * (rg >> 2) + 4 * (l >> 5);
    int jl = l & 31;
    int i, j; float wgt;
    if (tl == 0)      { i = il;      j = jl;      wgt = 1.f; }
    else if (tl == 1) { i = il;      j = jl + 32; wgt = 2.f; }  // symmetric quadrant
    else              { i = il + 32; j = jl + 32; wgt = 1.f; }
    if (i != j) {
      float sim = g[e] / sqrtf(n2[i] * n2[j]);
      if (sim > 0.2f && sim <= 1.0f) local += wgt * sim;
    }
  }
#pragma unroll
  for (int o = 32; o; o >>= 1) local += __shfl_xor(local, o, 64);
  if (lane == 0) wsum[wv] = local;
  __syncthreads();
  if (tid == 0) {
    float reg_sum = wsum[0] + wsum[1] + wsum[2] + wsum[3];
    float mse_sum = msum_s[0] + msum_s[1] + msum_s[2] + msum_s[3];
    out[0] = mse_sum * (1.0f / 8388608.0f) + 0.0005f * reg_sum;
  }
}

extern "C" void kernel_launch(void* const* d_in, const int* in_sizes, int n_in,
                              void* d_out, int out_size, void* d_ws, size_t ws_size,
                              hipStream_t stream) {
  const float* X = (const float*)d_in[0];
  const float* Y = (const float*)d_in[1];
  const float* W = (const float*)d_in[2];
  k_a<<<NB, BLOCK, 0, stream>>>(X, Y, W, (float*)d_ws);
  k_b<<<RED_BLOCKS, 256, 0, stream>>>((float*)d_ws, (float*)d_out);
}

// Round 7
// 58.657 us; speedup vs baseline: 1.7810x; 1.3008x over previous
//
#include <hip/hip_runtime.h>

typedef __attribute__((ext_vector_type(8)))  short   short8;
typedef __attribute__((ext_vector_type(4)))  unsigned uint4v;
typedef __attribute__((ext_vector_type(16))) float   f32x16;
typedef __attribute__((ext_vector_type(4)))  float   f4;

constexpr int GRAM_BLOCKS = 256;
constexpr int MSE_BLOCKS  = 256;
constexpr int BLOCK       = 512;          // 8 waves; 2 blocks/CU -> 16 waves/CU
constexpr int CHUNK_F     = 3072;         // 16 slabs x 192 floats = 12 KiB
constexpr int CPW         = 8;            // 256 blocks * 8 waves * 8 = 16384 chunks
constexpr int RED_BLOCKS  = 96;
constexpr int MSE_THREADS = MSE_BLOCKS * BLOCK;  // 131072 -> exactly 16 f4 iters

// ws float-offsets:
//   [0..256)     MSE per-block partials (plain stores)
//   [256..352)   96 k_b flags (writers store 1 w/ release; block0 resets 0)
//   [512..3584)  gram_final (3072)
//   [4096..4096+256*3072) per-block gram partial tiles (plain stores)
constexpr int MSE_OFF  = 0;
constexpr int FLAG_OFF = 256;
constexpr int GF_OFF   = 512;
constexpr int PART_OFF = 4096;

struct F3 { float v[3]; };                 // 12B -> global_load_dwordx3
struct Chunk { F3 a0[4], a1[4], b0[4], b1[4]; };

// pack two f32 -> one u32 of 2 bf16 (round-half-up): 2 add + 1 v_perm
__device__ __forceinline__ unsigned pk_bf16(float a, float b) {
  unsigned a2 = __builtin_bit_cast(unsigned, a) + 0x8000u;
  unsigned b2 = __builtin_bit_cast(unsigned, b) + 0x8000u;
  return __builtin_amdgcn_perm(b2, a2, 0x07060302u);
}

__device__ __forceinline__ void load_chunk(const float* __restrict__ W, int c,
                                           int laneoff, Chunk& ch) {
  const float* s = W + (size_t)c * CHUNK_F + laneoff;
#pragma unroll
  for (int bp = 0; bp < 4; ++bp) {
    const float* p = s + bp * 384;     // slab pair (2bp, 2bp+1) of this half
    ch.a0[bp] = *(const F3*)(p);       // slab even, row r
    ch.a1[bp] = *(const F3*)(p + 96);  // slab even, row r+32
    ch.b0[bp] = *(const F3*)(p + 192); // slab odd,  row r
    ch.b1[bp] = *(const F3*)(p + 288); // slab odd,  row r+32
  }
}

__device__ __forceinline__ void mac_chunk(const Chunk& c, f32x16& a00, f32x16& a01,
                                          f32x16& a11) {
#pragma unroll
  for (int k = 0; k < 3; ++k) {
    unsigned fl[4], fh[4];
#pragma unroll
    for (int bp = 0; bp < 4; ++bp) {
      fl[bp] = pk_bf16(c.a0[bp].v[k], c.b0[bp].v[k]);
      fh[bp] = pk_bf16(c.a1[bp].v[k], c.b1[bp].v[k]);
    }
    uint4v vl = {fl[0], fl[1], fl[2], fl[3]};
    uint4v vh = {fh[0], fh[1], fh[2], fh[3]};
    short8 lo = __builtin_bit_cast(short8, vl);
    short8 hv = __builtin_bit_cast(short8, vh);
    a00 = __builtin_amdgcn_mfma_f32_32x32x16_bf16(lo, lo, a00, 0, 0, 0);
    a01 = __builtin_amdgcn_mfma_f32_32x32x16_bf16(lo, hv, a01, 0, 0, 0);
    a11 = __builtin_amdgcn_mfma_f32_32x32x16_bf16(hv, hv, a11, 0, 0, 0);
  }
}

__global__ __launch_bounds__(BLOCK, 4) void k_a(
    const float* __restrict__ X, const float* __restrict__ Y,
    const float* __restrict__ W, float* __restrict__ ws) {
  __shared__ __align__(16) float red[4][3072];   // 48 KiB
  const int bid  = blockIdx.x;
  const int tid  = threadIdx.x;
  const int wave = tid >> 6;
  const int lane = tid & 63;

  if (bid >= GRAM_BLOCKS) {
    // ---------------- MSE partial (nontemporal; plain per-block store) ----------
    const unsigned t0 = (unsigned)((bid - GRAM_BLOCKS) * BLOCK + tid);
    const f4* x4 = (const f4*)X;
    const f4* y4 = (const f4*)Y;
    float acc = 0.f;
#pragma unroll 8
    for (int it = 0; it < 16; ++it) {
      unsigned i = t0 + (unsigned)it * (unsigned)MSE_THREADS;
      f4 a = __builtin_nontemporal_load(x4 + i);
      f4 b = __builtin_nontemporal_load(y4 + i);
      float d0 = a[0] - b[0], d1 = a[1] - b[1], d2 = a[2] - b[2], d3 = a[3] - b[3];
      acc += d0 * d0 + d1 * d1 + d2 * d2 + d3 * d3;
    }
#pragma unroll
    for (int o = 32; o; o >>= 1) acc += __shfl_xor(acc, o, 64);
    __shared__ float fsum[8];
    if (lane == 0) fsum[wave] = acc;
    __syncthreads();
    if (tid == 0) {
      float m = 0.f;
#pragma unroll
      for (int wv = 0; wv < 8; ++wv) m += fsum[wv];
      ws[MSE_OFF + bid - GRAM_BLOCKS] = m;
    }
    return;
  }

  // ------------- Gram partial: static 8 chunks/wave, reg double-buffer ----------
  const int r    = lane & 31;
  const int hi   = lane >> 5;
  const int laneoff = hi * 1536 + 3 * r;   // (hi*8 slabs)*192 + row r
  const int c0 = (bid * 8 + wave) * CPW;

  f32x16 a00{}, a01{}, a11{};
  Chunk ca, cb;
  load_chunk(W, c0, laneoff, ca);
#pragma unroll
  for (int t = 0; t < CPW; t += 2) {
    load_chunk(W, c0 + t + 1, laneoff, cb);
    mac_chunk(ca, a00, a01, a11);
    if (t + 2 < CPW) load_chunk(W, c0 + t + 2, laneoff, ca);
    mac_chunk(cb, a00, a01, a11);
  }

  // -------- block reduce (waves 0-3 store, waves 4-7 add, combine, store) -------
  if (wave < 4) {
    float* dst = red[wave];
#pragma unroll
    for (int rg = 0; rg < 16; ++rg) {
      dst[       rg * 64 + lane] = a00[rg];
      dst[1024 + rg * 64 + lane] = a01[rg];
      dst[2048 + rg * 64 + lane] = a11[rg];
    }
  }
  __syncthreads();
  if (wave >= 4) {
    float* dst = red[wave - 4];
#pragma unroll
    for (int rg = 0; rg < 16; ++rg) {
      dst[       rg * 64 + lane] += a00[rg];
      dst[1024 + rg * 64 + lane] += a01[rg];
      dst[2048 + rg * 64 + lane] += a11[rg];
    }
  }
  __syncthreads();
  {
    const f4* r0 = (const f4*)&red[0][0];
    const f4* r1 = (const f4*)&red[1][0];
    const f4* r2 = (const f4*)&red[2][0];
    const f4* r3 = (const f4*)&red[3][0];
    f4* p4 = (f4*)(ws + PART_OFF + (size_t)bid * 3072);
#pragma unroll
    for (int q = tid; q < 768; q += BLOCK)
      p4[q] = (r0[q] + r1[q]) + (r2[q] + r3[q]);
  }
}

__global__ __launch_bounds__(256) void k_b(float* __restrict__ ws,
                                           float* __restrict__ out) {
  __shared__ float r2[4][32];
  __shared__ float g[3072];
  __shared__ float n2[64];
  __shared__ float msum_s[4];
  __shared__ float wsum[4];
  const int tid = threadIdx.x;
  const int lane = tid & 63, wv = tid >> 6, el = lane & 31, ph = lane >> 5;
  const int b = blockIdx.x;
  const int w0 = b * 32;
  int* flags = (int*)(ws + FLAG_OFF);

  // ---- reduce 256 partial tiles over this block's 32-col window ----
  const float* base = ws + PART_OFF + (size_t)(ph + 2 * wv) * 3072 + w0 + el;
  float acc = 0.f;
#pragma unroll 8
  for (int i = 0; i < 32; ++i) acc += base[(size_t)i * 24576];
  acc += __shfl_xor(acc, 32, 64);
  if (ph == 0) r2[wv][el] = acc;
  __syncthreads();
  if (tid < 32)
    ws[GF_OFF + w0 + tid] = r2[0][tid] + r2[1][tid] + r2[2][tid] + r2[3][tid];
  __syncthreads();   // drains stores before publishing
  if (tid == 0) {
    __threadfence();
    __hip_atomic_store(&flags[b], 1, __ATOMIC_RELEASE, __HIP_MEMORY_SCOPE_AGENT);
  }
  if (b != 0) return;

  // ---- block 0: wait for all 96 windows, then finalize ----
  if (tid < RED_BLOCKS)
    while (__hip_atomic_load(&flags[tid], __ATOMIC_RELAXED,
                             __HIP_MEMORY_SCOPE_AGENT) != 1)
      __builtin_amdgcn_s_sleep(8);
  __syncthreads();
  __threadfence();

  for (int e = tid; e < 3072; e += 256) g[e] = ws[GF_OFF + e];

  float m = ws[MSE_OFF + tid];
#pragma unroll
  for (int o = 32; o; o >>= 1) m += __shfl_xor(m, o, 64);
  if (lane == 0) msum_s[wv] = m;
  __syncthreads();

  // reset flags for the next replay (all writers provably done)
  if (tid < RED_BLOCKS) flags[tid] = 0;

  // C/D layout of 32x32 mfma: col = lane&31, row = (reg&3) + 8*(reg>>2) + 4*(lane>>5)
  for (int e = tid; e < 3072; e += 256) {
    int tl = e >> 10, rg = (e >> 6) & 15, l = e & 63;
    int il = (rg & 3) + 8 * (rg >> 2) + 4 * (l >> 5);
    int jl = l & 31;
    if (tl != 1 && il == jl) n2[il + (tl == 2 ? 32 : 0)] = g[e];
  }
  __syncthreads();

  float local = 0.f;
  for (int e = tid; e < 3072; e += 256) {
    int tl = e >> 10, rg = (e >> 6) & 15, l = e & 63;
    int il = (rg & 3) + 8 * (rg >> 2) + 4 * (l >> 5);
    int jl = l & 31;
    int i, j; float wgt;
    if (tl == 0)      { i = il;      j = jl;      wgt = 1.f; }
    else if (tl == 1) { i = il;      j = jl + 32; wgt = 2.f; }  // symmetric quadrant
    else              { i = il + 32; j = jl + 32; wgt = 1.f; }
    if (i != j) {
      float sim = g[e] / sqrtf(n2[i] * n2[j]);
      if (sim > 0.2f && sim <= 1.0f) local += wgt * sim;
    }
  }
#pragma unroll
  for (int o = 32; o; o >>= 1) local += __shfl_xor(local, o, 64);
  if (lane == 0) wsum[wv] = local;
  __syncthreads();
  if (tid == 0) {
    float reg_sum = wsum[0] + wsum[1] + wsum[2] + wsum[3];
    float mse_sum = msum_s[0] + msum_s[1] + msum_s[2] + msum_s[3];
    out[0] = mse_sum * (1.0f / 8388608.0f) + 0.0005f * reg_sum;
  }
}

extern "C" void kernel_launch(void* const* d_in, const int* in_sizes, int n_in,
                              void* d_out, int out_size, void* d_ws, size_t ws_size,
                              hipStream_t stream) {
  const float* X = (const float*)d_in[0];
  const float* Y = (const float*)d_in[1];
  const float* W = (const float*)d_in[2];
  k_a<<<GRAM_BLOCKS + MSE_BLOCKS, BLOCK, 0, stream>>>(X, Y, W, (float*)d_ws);
  k_b<<<RED_BLOCKS, 256, 0, stream>>>((float*)d_ws, (float*)d_out);
}